// Round 1
// baseline (13096.208 us; speedup 1.0000x reference)
//
#include <hip/hip_runtime.h>
#include <hip/hip_bf16.h>

typedef unsigned short u16;
typedef unsigned int   u32;
typedef unsigned long long u64;
typedef __attribute__((ext_vector_type(8))) short short8;
typedef __attribute__((ext_vector_type(4))) float f32x4;

__device__ __forceinline__ float bf2f(u16 u) {
  union { u32 i; float f; } v; v.i = ((u32)u) << 16; return v.f;
}
__device__ __forceinline__ u16 f2bf(float f) {
  union { float f; u32 i; } v; v.f = f;
  return (u16)((v.i + 0x7FFFu + ((v.i >> 16) & 1u)) >> 16);
}

typedef const __attribute__((address_space(1))) u32* gas_t;
typedef __attribute__((address_space(3)))       u32* las_t;
__device__ __forceinline__ void gld16(const void* g, void* l) {
  __builtin_amdgcn_global_load_lds((gas_t)g, (las_t)l, 16, 0, 0);
}

// ---------------- elementwise prep ----------------
__global__ __launch_bounds__(256) void cast_kernel(const float* __restrict__ src,
                                                   u16* __restrict__ dst, int n) {
  int i = (blockIdx.x * 256 + threadIdx.x) * 4;
  if (i >= n) return;
  float4 v = *(const float4*)(src + i);
  uint2 o;
  o.x = (u32)f2bf(v.x) | ((u32)f2bf(v.y) << 16);
  o.y = (u32)f2bf(v.z) | ((u32)f2bf(v.w) << 16);
  *(uint2*)(dst + i) = o;
}

// dst[c][r] = bf16(src[r][c]);  R,C multiples of 32
__global__ __launch_bounds__(256) void tcast_kernel(const float* __restrict__ src,
                                                    u16* __restrict__ dst, int R, int C) {
  __shared__ u16 tile[32][33];
  int c0 = blockIdx.x * 32, r0 = blockIdx.y * 32;
  for (int dy = threadIdx.y; dy < 32; dy += 8)
    tile[dy][threadIdx.x] = f2bf(src[(size_t)(r0 + dy) * C + c0 + threadIdx.x]);
  __syncthreads();
  for (int dy = threadIdx.y; dy < 32; dy += 8)
    dst[(size_t)(c0 + dy) * R + r0 + threadIdx.x] = tile[threadIdx.x][dy];
}

// LN over D=512, input [B][S][D] f32, output time-major [S][B][D] bf16
__global__ __launch_bounds__(256) void ln0_kernel(const float* __restrict__ in,
                                                  const float* __restrict__ g,
                                                  const float* __restrict__ be,
                                                  u16* __restrict__ xout) {
  int m = blockIdx.x;            // b*1024 + s
  int b = m >> 10, s = m & 1023;
  int i = threadIdx.x * 2;
  float2 v = *(const float2*)(in + (size_t)m * 512 + i);
  float sum = v.x + v.y, sq = v.x * v.x + v.y * v.y;
  for (int o = 32; o > 0; o >>= 1) { sum += __shfl_down(sum, o); sq += __shfl_down(sq, o); }
  __shared__ float red[10];
  int w = threadIdx.x >> 6, lane = threadIdx.x & 63;
  if (!lane) { red[w] = sum; red[w + 4] = sq; }
  __syncthreads();
  if (threadIdx.x == 0) {
    sum = red[0] + red[1] + red[2] + red[3];
    sq  = red[4] + red[5] + red[6] + red[7];
    float mu = sum * (1.f / 512.f), var = sq * (1.f / 512.f) - mu * mu;
    red[8] = mu; red[9] = rsqrtf(var + 1e-5f);
  }
  __syncthreads();
  float mu = red[8], rs = red[9];
  u32 o0 = (u32)f2bf((v.x - mu) * rs * g[i] + be[i]) |
           ((u32)f2bf((v.y - mu) * rs * g[i + 1] + be[i + 1]) << 16);
  *(u32*)(xout + (size_t)(s * 16 + b) * 512 + i) = o0;
}

// out = inputs + h(time-major);  y = bf16(LN(out))
__global__ __launch_bounds__(256) void resid_ln1_kernel(const float* __restrict__ in,
                                                        const u16* __restrict__ hrec,
                                                        const float* __restrict__ g,
                                                        const float* __restrict__ be,
                                                        float* __restrict__ outf,
                                                        u16* __restrict__ y) {
  int m = blockIdx.x;            // b*1024 + s
  int b = m >> 10, s = m & 1023;
  int i = threadIdx.x * 2;
  float2 v = *(const float2*)(in + (size_t)m * 512 + i);
  u32 hu = *(const u32*)(hrec + (size_t)(s * 16 + b) * 512 + i);
  v.x += bf2f((u16)(hu & 0xffff));
  v.y += bf2f((u16)(hu >> 16));
  *(float2*)(outf + (size_t)m * 512 + i) = v;
  float sum = v.x + v.y, sq = v.x * v.x + v.y * v.y;
  for (int o = 32; o > 0; o >>= 1) { sum += __shfl_down(sum, o); sq += __shfl_down(sq, o); }
  __shared__ float red[10];
  int w = threadIdx.x >> 6, lane = threadIdx.x & 63;
  if (!lane) { red[w] = sum; red[w + 4] = sq; }
  __syncthreads();
  if (threadIdx.x == 0) {
    sum = red[0] + red[1] + red[2] + red[3];
    sq  = red[4] + red[5] + red[6] + red[7];
    float mu = sum * (1.f / 512.f), var = sq * (1.f / 512.f) - mu * mu;
    red[8] = mu; red[9] = rsqrtf(var + 1e-5f);
  }
  __syncthreads();
  float mu = red[8], rs = red[9];
  u32 o0 = (u32)f2bf((v.x - mu) * rs * g[i] + be[i]) |
           ((u32)f2bf((v.y - mu) * rs * g[i + 1] + be[i + 1]) << 16);
  *(u32*)(y + (size_t)m * 512 + i) = o0;
}

// ---------------- bf16 MFMA GEMM: C[M][N] = A[M][K] * Bt[N][K]^T ----------------
// EPI 0: bf16 out = acc+bias; EPI 1: bf16 out = gelu(acc+bias); EPI 2: f32 out = acc+bias+resid
template <int EPI>
__global__ __launch_bounds__(256, 2)
void gemm_bt(const u16* __restrict__ A, const u16* __restrict__ Bt,
             void* __restrict__ Out, const float* __restrict__ bias,
             const float* __restrict__ resid, int M, int N, int K) {
  __shared__ u16 As[128 * 64];
  __shared__ u16 Bs[128 * 64];
  const int bn = blockIdx.x, bm = blockIdx.y;
  const int tid = threadIdx.x;
  const int w = tid >> 6, lane = tid & 63;
  const int wr = w >> 1, wc = w & 1;
  const int col = lane & 15, kg = lane >> 4;
  const int l8 = lane >> 3, l7 = lane & 7;
  f32x4 acc[4][4];
#pragma unroll
  for (int i = 0; i < 4; ++i)
#pragma unroll
    for (int j = 0; j < 4; ++j) acc[i][j] = (f32x4){0.f, 0.f, 0.f, 0.f};

  for (int k0 = 0; k0 < K; k0 += 64) {
    __syncthreads();
#pragma unroll
    for (int i = 0; i < 4; ++i) {
      int q = w * 4 + i;
      int row = q * 8 + l8;
      int cswz = (l7 * 16) ^ ((row & 7) << 4);
      gld16((const char*)A + ((size_t)(bm * 128 + row) * K + k0) * 2 + cswz,
            (char*)As + q * 1024);
      gld16((const char*)Bt + ((size_t)(bn * 128 + row) * K + k0) * 2 + cswz,
            (char*)Bs + q * 1024);
    }
    asm volatile("s_waitcnt vmcnt(0)" ::: "memory");
    __syncthreads();
#pragma unroll
    for (int kc = 0; kc < 2; ++kc) {
      short8 af[4], bfr[4];
      int cb = kc * 64 + kg * 16;
#pragma unroll
      for (int mi = 0; mi < 4; ++mi) {
        int r = wr * 64 + mi * 16 + col;
        af[mi] = *(const short8*)((const char*)As + r * 128 + (cb ^ ((r & 7) << 4)));
      }
#pragma unroll
      for (int ni = 0; ni < 4; ++ni) {
        int r = wc * 64 + ni * 16 + col;
        bfr[ni] = *(const short8*)((const char*)Bs + r * 128 + (cb ^ ((r & 7) << 4)));
      }
#pragma unroll
      for (int mi = 0; mi < 4; ++mi)
#pragma unroll
        for (int ni = 0; ni < 4; ++ni)
          acc[mi][ni] = __builtin_amdgcn_mfma_f32_16x16x32_bf16(af[mi], bfr[ni], acc[mi][ni], 0, 0, 0);
    }
  }
#pragma unroll
  for (int ni = 0; ni < 4; ++ni) {
    int gn = bn * 128 + wc * 64 + ni * 16 + col;
    float bv = bias ? bias[gn] : 0.f;
#pragma unroll
    for (int mi = 0; mi < 4; ++mi) {
      int gmb = bm * 128 + wr * 64 + mi * 16 + kg * 4;
#pragma unroll
      for (int j = 0; j < 4; ++j) {
        float v = acc[mi][ni][j] + bv;
        size_t idx = (size_t)(gmb + j) * N + gn;
        if (EPI == 0) {
          ((u16*)Out)[idx] = f2bf(v);
        } else if (EPI == 1) {
          float gel = 0.5f * v * (1.f + erff(v * 0.7071067811865476f));
          ((u16*)Out)[idx] = f2bf(gel);
        } else {
          ((float*)Out)[idx] = v + resid[idx];
        }
      }
    }
  }
}

// ---------------- persistent GRU recurrence (one layer) ----------------
// 8 blocks x 4 waves. Block owns d-slice [blk*64, blk*64+64); wave owns 16 of it,
// holding W_hh rows for (r,z,n) of that 16-slice as MFMA B-fragments (192 VGPRs).
// Per step: all blocks exchange h via agent-scope (write-through) stores + flags.
__global__ __launch_bounds__(256, 1)
void rec_kernel(const u16* __restrict__ gi, const u16* __restrict__ whh,
                const float* __restrict__ bhh, const float* __restrict__ h0,
                u16* __restrict__ hbuf, int* __restrict__ flags,
                u16* __restrict__ xout) {
  __shared__ u16 hs[16 * 512];    // staged h(t), rows=batch, 16 KB
  __shared__ u16 hx[4][16][16];   // per-wave store bounce
  const int blk = blockIdx.x;
  const int tid = threadIdx.x;
  const int w = tid >> 6, lane = tid & 63;
  const int col = lane & 15, kg = lane >> 4;
  const int d = blk * 64 + w * 16 + col;

  // preload W_hh fragments: B-frag for gate g, k-chunk kc: lane col -> row g*512+d
  short8 wf0[16], wf1[16], wf2[16];
  {
    const u16* r0 = whh + (size_t)(0 * 512 + d) * 512;
    const u16* r1 = whh + (size_t)(1 * 512 + d) * 512;
    const u16* r2 = whh + (size_t)(2 * 512 + d) * 512;
#pragma unroll
    for (int kc = 0; kc < 16; ++kc) {
      wf0[kc] = *(const short8*)(r0 + kc * 32 + kg * 8);
      wf1[kc] = *(const short8*)(r1 + kc * 32 + kg * 8);
      wf2[kc] = *(const short8*)(r2 + kc * 32 + kg * 8);
    }
  }
  const float bh0 = bhh[d], bh1 = bhh[512 + d], bh2 = bhh[1024 + d];
  float hprev[4];
#pragma unroll
  for (int j = 0; j < 4; ++j) hprev[j] = h0[(kg * 4 + j) * 512 + d];

  for (int t = 0; t < 1024; ++t) {
    // gi loads (independent of h) issued first to hide HBM latency under the spin
    float gir[3][4];
#pragma unroll
    for (int gte = 0; gte < 3; ++gte)
#pragma unroll
      for (int j = 0; j < 4; ++j)
        gir[gte][j] = bf2f(gi[((size_t)t * 16 + kg * 4 + j) * 1536 + gte * 512 + d]);

    if (t > 0) {
      while (true) {
        int f = (lane < 8)
                  ? __hip_atomic_load(flags + lane, __ATOMIC_RELAXED, __HIP_MEMORY_SCOPE_AGENT)
                  : 0x7fffffff;
        if (__all(f >= t)) break;
        __builtin_amdgcn_s_sleep(2);
      }
      __builtin_amdgcn_fence(__ATOMIC_ACQUIRE, "agent");  // invalidate stale L1/L2
    }
    // stage h(t) -> LDS (linear dest, inverse-swizzled source; read-side XOR matches)
    {
      const char* hb = (const char*)(hbuf + (size_t)(t & 1) * 8192);
#pragma unroll
      for (int r = 0; r < 4; ++r) {
        int row = w * 4 + r;
        gld16(hb + row * 1024 + ((lane * 16) ^ ((row & 7) << 4)), (char*)hs + row * 1024);
      }
    }
    asm volatile("s_waitcnt vmcnt(0)" ::: "memory");
    __syncthreads();

    f32x4 ar = {0.f, 0.f, 0.f, 0.f}, az = ar, an = ar;
#pragma unroll
    for (int kc = 0; kc < 16; ++kc) {
      int rb = col;                    // batch row
      int cb = kc * 64 + kg * 16;
      short8 a = *(const short8*)((const char*)hs + rb * 1024 + (cb ^ ((rb & 7) << 4)));
      ar = __builtin_amdgcn_mfma_f32_16x16x32_bf16(a, wf0[kc], ar, 0, 0, 0);
      az = __builtin_amdgcn_mfma_f32_16x16x32_bf16(a, wf1[kc], az, 0, 0, 0);
      an = __builtin_amdgcn_mfma_f32_16x16x32_bf16(a, wf2[kc], an, 0, 0, 0);
    }
    // gates; keep h in f32 in-lane (only MFMA input is bf16-quantized)
#pragma unroll
    for (int j = 0; j < 4; ++j) {
      float rg = 1.f / (1.f + expf(-(gir[0][j] + ar[j] + bh0)));
      float zg = 1.f / (1.f + expf(-(gir[1][j] + az[j] + bh1)));
      float ng = tanhf(gir[2][j] + rg * (an[j] + bh2));
      float hn = (1.f - zg) * ng + zg * hprev[j];
      hprev[j] = hn;
      hx[w][kg * 4 + j][col] = f2bf(hn);
    }
    __syncthreads();
    // packed 8B stores: hbuf via agent-scope write-through atomics, xout plain
    {
      int b = lane >> 2, dq = lane & 3;
      int dd = blk * 64 + w * 16 + dq * 4;
      u64 pk = *(const u64*)&hx[w][b][dq * 4];
      u16* hw = hbuf + (size_t)((t + 1) & 1) * 8192;
      __hip_atomic_store((u64*)(hw + (size_t)b * 512 + dd), pk,
                         __ATOMIC_RELAXED, __HIP_MEMORY_SCOPE_AGENT);
      *(u64*)(xout + ((size_t)t * 16 + b) * 512 + dd) = pk;
    }
    __syncthreads();  // barrier drains each wave's vmcnt -> all stores complete
    if (tid == 0) {
      __builtin_amdgcn_fence(__ATOMIC_RELEASE, "agent");  // L2 writeback (belt&suspenders)
      __hip_atomic_store(flags + blk, t + 1, __ATOMIC_RELAXED, __HIP_MEMORY_SCOPE_AGENT);
    }
  }
}

// ---------------- host ----------------
extern "C" void kernel_launch(void* const* d_in, const int* in_sizes, int n_in,
                              void* d_out, int out_size, void* d_ws, size_t ws_size,
                              hipStream_t stream) {
  const float* inp = (const float*)d_in[0];
  const float* h0  = (const float*)d_in[1];
  const float* wih = (const float*)d_in[2];
  const float* whh = (const float*)d_in[3];
  const float* bih = (const float*)d_in[4];
  const float* bhh = (const float*)d_in[5];
  const float* g0  = (const float*)d_in[6];
  const float* be0 = (const float*)d_in[7];
  const float* g1  = (const float*)d_in[8];
  const float* be1 = (const float*)d_in[9];
  const float* w1  = (const float*)d_in[10];
  const float* b1  = (const float*)d_in[11];
  const float* w2  = (const float*)d_in[12];
  const float* b2  = (const float*)d_in[13];
  float* out = (float*)d_out;

  char* p = (char*)d_ws;
  auto alloc = [&](size_t bytes) {
    char* r = p;
    p += (bytes + 255) & ~(size_t)255;
    return r;
  };
  u16* xa    = (u16*)alloc(16384ull * 512 * 2);
  u16* xb    = (u16*)alloc(16384ull * 512 * 2);
  u16* gib   = (u16*)alloc(16384ull * 1536 * 2);
  u16* mid   = (u16*)alloc(16384ull * 2048 * 2);
  float* outf = (float*)alloc(16384ull * 512 * 4);
  u16* wihb  = (u16*)alloc(3ull * 1536 * 512 * 2);
  u16* whhb  = (u16*)alloc(3ull * 1536 * 512 * 2);
  u16* w1t   = (u16*)alloc(2048ull * 512 * 2);
  u16* w2t   = (u16*)alloc(512ull * 2048 * 2);
  u16* hbuf  = (u16*)alloc(3ull * 2 * 16 * 512 * 2);
  int* flags = (int*)alloc(256);

  hipMemsetAsync(flags, 0, 256, stream);
  cast_kernel<<<(3 * 1536 * 512) / 1024, 256, 0, stream>>>(wih, wihb, 3 * 1536 * 512);
  cast_kernel<<<(3 * 1536 * 512) / 1024, 256, 0, stream>>>(whh, whhb, 3 * 1536 * 512);
  for (int l = 0; l < 3; ++l)
    cast_kernel<<<8, 256, 0, stream>>>(h0 + l * 8192, hbuf + (size_t)l * 16384, 8192);
  tcast_kernel<<<dim3(2048 / 32, 512 / 32), dim3(32, 8), 0, stream>>>(w1, w1t, 512, 2048);
  tcast_kernel<<<dim3(512 / 32, 2048 / 32), dim3(32, 8), 0, stream>>>(w2, w2t, 2048, 512);
  ln0_kernel<<<16384, 256, 0, stream>>>(inp, g0, be0, xa);

  for (int l = 0; l < 3; ++l) {
    const u16* xin = (l & 1) ? xb : xa;  // l0:xa l1:xb l2:xa
    u16* xo        = (l & 1) ? xa : xb;  // l0:xb l1:xa l2:xb
    gemm_bt<0><<<dim3(12, 128), 256, 0, stream>>>(xin, wihb + (size_t)l * 1536 * 512,
                                                  (void*)gib, bih + l * 1536, nullptr,
                                                  16384, 1536, 512);
    rec_kernel<<<8, 256, 0, stream>>>(gib, whhb + (size_t)l * 1536 * 512, bhh + l * 1536,
                                      h0 + l * 8192, hbuf + (size_t)l * 16384,
                                      flags + l * 8, xo);
  }
  resid_ln1_kernel<<<16384, 256, 0, stream>>>(inp, xb, g1, be1, outf, xa);
  gemm_bt<1><<<dim3(16, 128), 256, 0, stream>>>(xa, w1t, (void*)mid, b1, nullptr,
                                                16384, 2048, 512);
  gemm_bt<2><<<dim3(4, 128), 256, 0, stream>>>(mid, w2t, (void*)out, b2, outf,
                                               16384, 512, 2048);
}